// Round 12
// baseline (781.209 us; speedup 1.0000x reference)
//
#include <hip/hip_runtime.h>
#include <hip/hip_bf16.h>
#include <cstdint>
#include <cstddef>

// Problem constants
#define B_DIM 4
#define H_DIM 200
#define W_DIM 176
#define CCH 256
#define NPP 16384        // points per batch entry (N)
#define NPTS 65536       // total points (P)
#define HW 35200         // H*W
#define S_TOT 140800     // B*H*W
#define EPS 1e-3f
#define INV_S (1.0f/140800.0f)

typedef unsigned short ushort_t;
typedef __attribute__((ext_vector_type(8))) short bf16x8;
typedef __attribute__((ext_vector_type(4))) float f32x4;

__device__ __forceinline__ ushort_t f2bf(float f) {
    __hip_bfloat16 h = __float2bfloat16(f);   // RNE
    return *(ushort_t*)&h;
}
__device__ __forceinline__ float bf2f(ushort_t u) {
    __hip_bfloat16 h = *(__hip_bfloat16*)&u;
    return __bfloat162float(h);
}

__device__ __forceinline__ void async16(const void* g, void* l) {
    __builtin_amdgcn_global_load_lds(
        (const __attribute__((address_space(1))) unsigned int*)g,
        (__attribute__((address_space(3))) unsigned int*)l,
        16, 0, 0);
}

// counted waits (T4)
__device__ __forceinline__ void wait_vmcnt0()  { asm volatile("s_waitcnt vmcnt(0)" ::: "memory"); }
__device__ __forceinline__ void wait_vmcnt4()  { asm volatile("s_waitcnt vmcnt(4)" ::: "memory"); }
__device__ __forceinline__ void wait_vmcnt8()  { asm volatile("s_waitcnt vmcnt(8)" ::: "memory"); }
__device__ __forceinline__ void wait_vmcnt10() { asm volatile("s_waitcnt vmcnt(10)" ::: "memory"); }
__device__ __forceinline__ void wait_lgkm0()   { asm volatile("s_waitcnt lgkmcnt(0)" ::: "memory"); }
__device__ __forceinline__ void memfence_compiler() { asm volatile("" ::: "memory"); }

// BN+ReLU on 8 packed bf16 (sc/sh pre-offset to the channel base)
__device__ __forceinline__ bf16x8 bnrelu8(bf16x8 a, const float* __restrict__ sc,
                                          const float* __restrict__ sh) {
    bf16x8 r;
#pragma unroll
    for (int e = 0; e < 8; ++e) {
        float f = bf2f((ushort_t)a[e]);
        r[e] = (short)f2bf(fmaxf(0.f, f * sc[e] + sh[e]));
    }
    return r;
}

// row-scalar multiply on 8 packed bf16 (sp = pooled * factor)
__device__ __forceinline__ bf16x8 mul8(bf16x8 a, float f) {
    bf16x8 r;
#pragma unroll
    for (int e = 0; e < 8; ++e)
        r[e] = (short)f2bf(bf2f((ushort_t)a[e]) * f);
    return r;
}

// bijective XCD swizzle (m204)
__device__ __forceinline__ int xcd_virt(int fid, int n) {
    int q = n >> 3, r = n & 7;
    int xcd = fid & 7, idx = fid >> 3;
    int base = (xcd < r) ? xcd * (q + 1) : r * (q + 1) + (xcd - r) * q;
    return base + idx;
}

// ---------------------------------------------------------------- transpose --
__global__ __launch_bounds__(256) void k_transpose(
    const float* __restrict__ feats, ushort_t* __restrict__ FT)
{
    __shared__ float lds[64][65];
    const int b  = blockIdx.z;
    const int c0 = blockIdx.y * 64;
    const int n0 = blockIdx.x * 64;
    const int tid = threadIdx.x;
#pragma unroll
    for (int i = 0; i < 16; ++i) {
        int idx = i * 256 + tid;
        int cr = idx >> 6, nc = idx & 63;
        lds[cr][nc] = feats[((size_t)b * 256 + c0 + cr) * NPP + n0 + nc];
    }
    __syncthreads();
#pragma unroll
    for (int i = 0; i < 16; ++i) {
        int idx = i * 256 + tid;
        int nr = idx >> 6, cc = idx & 63;
        FT[((size_t)b * NPP + n0 + nr) * CCH + c0 + cc] = f2bf(lds[cc][nr]);
    }
}

// ---------------------------------------------------------------- index build
__global__ __launch_bounds__(256) void k_buildidx(
    const int* __restrict__ cb, const int* __restrict__ cy,
    const int* __restrict__ cx, int* __restrict__ cnt,
    int* __restrict__ pslot, int* __restrict__ vid)
{
    int p = blockIdx.x * 256 + threadIdx.x;
    int v = cb[p] * HW + cy[p] * W_DIM + cx[p];
    vid[p] = v;
    int r = atomicAdd(&cnt[v], 1);
    if (r < 8) pslot[v * 8 + r] = p;
}

// ---------------------------------------------------------------- pool gather
__global__ __launch_bounds__(256) void k_poolgather(
    const ushort_t* __restrict__ FT, const int* __restrict__ cnt,
    const int* __restrict__ pslot, const int* __restrict__ vid,
    ushort_t* __restrict__ Pb)
{
    const int wave = threadIdx.x >> 6;
    const int lane = threadIdx.x & 63;
    const int v = blockIdx.x * 4 + wave;
    const int c = cnt[v];
    float a0 = 0.f, a1 = 0.f, a2 = 0.f, a3 = 0.f;
    if (c <= 8) {
        for (int k = 0; k < c; ++k) {
            int p = pslot[v * 8 + k];
            ushort4 r = ((const ushort4*)(FT + (size_t)p * CCH))[lane];
            a0 += bf2f(r.x); a1 += bf2f(r.y); a2 += bf2f(r.z); a3 += bf2f(r.w);
        }
    } else {
        for (int p = 0; p < NPTS; ++p)
            if (vid[p] == v) {
                ushort4 r = ((const ushort4*)(FT + (size_t)p * CCH))[lane];
                a0 += bf2f(r.x); a1 += bf2f(r.y); a2 += bf2f(r.z); a3 += bf2f(r.w);
            }
    }
    float inv = c ? 1.f / (float)c : 0.f;
    ushort4 o;
    o.x = f2bf(a0 * inv); o.y = f2bf(a1 * inv);
    o.z = f2bf(a2 * inv); o.w = f2bf(a3 * inv);
    ((ushort4*)(Pb + (size_t)v * CCH))[lane] = o;
}

// ---------------------------------------------------------------- GEMM (L1) --
__global__ __launch_bounds__(256) void k_gemmma(
    const ushort_t* __restrict__ X, const ushort_t* __restrict__ Wt,
    ushort_t* __restrict__ Y1, ushort_t* __restrict__ Y2, int ldY,
    int bnh, int nblocks,
    float* __restrict__ acc0, float* __restrict__ acc1, int sqoff)
{
    __shared__ ushort_t Asm[2][128 * 64];
    __shared__ ushort_t Bsm[2][128 * 64];
    const int tid  = threadIdx.x;
    const int w    = tid >> 6;
    const int lane = tid & 63;
    const int virt = xcd_virt(blockIdx.x, nblocks);
    const int pi   = virt / bnh;
    const int bn   = (virt % bnh) * 128;
    const int bm   = pi * 128;
    const int wr   = (w >> 1) * 64;
    const int wc   = (w & 1) * 64;

    size_t aoff[4]; size_t boff[4];
#pragma unroll
    for (int j = 0; j < 4; ++j) {
        int row  = 32 * j + 8 * w + (lane >> 3);
        int qlog = (lane & 7) ^ (row & 7);
        aoff[j] = (size_t)(bm + row) * 256 + qlog * 8;
        boff[j] = (size_t)(bn + row) * 256 + qlog * 8;
    }
    const int lo = (w * 8) * 64;

#pragma unroll
    for (int j = 0; j < 4; ++j) async16(X + aoff[j], &Asm[0][(j * 32) * 64 + lo]);
#pragma unroll
    for (int j = 0; j < 4; ++j) async16(Wt + boff[j], &Bsm[0][(j * 32) * 64 + lo]);

    f32x4 acc[4][4] = {};
    for (int kc = 0; kc < 4; ++kc) {
        if (kc < 3) {
#pragma unroll
            for (int j = 0; j < 4; ++j)
                async16(X + aoff[j] + (kc + 1) * 64, &Asm[(kc + 1) & 1][(j * 32) * 64 + lo]);
#pragma unroll
            for (int j = 0; j < 4; ++j)
                async16(Wt + boff[j] + (kc + 1) * 64, &Bsm[(kc + 1) & 1][(j * 32) * 64 + lo]);
            wait_vmcnt8();
        } else {
            wait_vmcnt0();
        }
        __builtin_amdgcn_s_barrier();
        const ushort_t* Ac = Asm[kc & 1];
        const ushort_t* Bc = Bsm[kc & 1];
        __builtin_amdgcn_s_setprio(1);
#pragma unroll
        for (int ks = 0; ks < 2; ++ks) {
            const int q = ks * 4 + (lane >> 4);
            bf16x8 af[4], bfr[4];
#pragma unroll
            for (int i = 0; i < 4; ++i) {
                int ra = wr + i * 16 + (lane & 15);
                af[i] = *(const bf16x8*)&Ac[ra * 64 + ((q ^ (ra & 7)) * 8)];
            }
#pragma unroll
            for (int jn = 0; jn < 4; ++jn) {
                int rn = wc + jn * 16 + (lane & 15);
                bfr[jn] = *(const bf16x8*)&Bc[rn * 64 + ((q ^ (rn & 7)) * 8)];
            }
#pragma unroll
            for (int i = 0; i < 4; ++i)
#pragma unroll
                for (int jn = 0; jn < 4; ++jn)
                    acc[i][jn] = __builtin_amdgcn_mfma_f32_16x16x32_bf16(
                        af[i], bfr[jn], acc[i][jn], 0, 0, 0);
        }
        __builtin_amdgcn_s_setprio(0);
        memfence_compiler();
        __builtin_amdgcn_s_barrier();
    }
    __syncthreads();

    const int crow0 = bm + wr + (lane >> 4) * 4;
    const int ccol0 = bn + wc + (lane & 15);
    float ls[4] = {}, lq[4] = {};
#pragma unroll
    for (int i = 0; i < 4; ++i)
#pragma unroll
        for (int jn = 0; jn < 4; ++jn) {
            int col = ccol0 + jn * 16;
#pragma unroll
            for (int r = 0; r < 4; ++r) {
                float v = acc[i][jn][r];
                ls[jn] += v; lq[jn] += v * v;
                size_t row = (size_t)(crow0 + i * 16 + r);
                if (col < 256) Y1[row * ldY + col] = f2bf(v);
                else           Y2[row * ldY + col - 256] = f2bf(v);
            }
        }
#pragma unroll
    for (int jn = 0; jn < 4; ++jn) {
        ls[jn] += __shfl_xor(ls[jn], 16, 64); ls[jn] += __shfl_xor(ls[jn], 32, 64);
        lq[jn] += __shfl_xor(lq[jn], 16, 64); lq[jn] += __shfl_xor(lq[jn], 32, 64);
    }
    float* red = (float*)&Asm[0][0];
    if (lane < 16) {
#pragma unroll
        for (int jn = 0; jn < 4; ++jn) {
            red[((w * 16 + lane) * 4 + jn) * 2 + 0] = ls[jn];
            red[((w * 16 + lane) * 4 + jn) * 2 + 1] = lq[jn];
        }
    }
    __syncthreads();
    if (tid < 256) {
        int colhalf = tid & 127, isq = tid >> 7;
        int pair = colhalf >> 6, within = colhalf & 63;
        int l16 = within & 15, jn = within >> 4;
        int w0 = pair ? 1 : 0, w1 = pair ? 3 : 2;
        float s = red[((w0 * 16 + l16) * 4 + jn) * 2 + isq]
                + red[((w1 * 16 + l16) * 4 + jn) * 2 + isq];
        int colg = bn + colhalf;
        float* t = (colg < 256) ? acc0 : acc1;
        atomicAdd(&t[(colg & 255) + isq * sqoff], s);
    }
}

// ------------------------------------------------------- GEMM + BN (grouped) -
// blocks [0,2200): SH-L2 (N=256, bnh=2); blocks [2200,3300): G-L2 (N=128).
__global__ __launch_bounds__(256) void k_gemmma_bn2(
    const ushort_t* __restrict__ X1, const float* __restrict__ a1In,
    const float* __restrict__ g1, const float* __restrict__ b1,
    const ushort_t* __restrict__ W1, ushort_t* __restrict__ Y1o,
    float* __restrict__ a1Out,
    const ushort_t* __restrict__ X2, const float* __restrict__ a2In,
    const float* __restrict__ g2, const float* __restrict__ b2,
    const ushort_t* __restrict__ W2, ushort_t* __restrict__ Y2o,
    float* __restrict__ a2Out)
{
    const bool sh = blockIdx.x < 2200;
    const ushort_t* X   = sh ? X1 : X2;
    const float* accIn  = sh ? a1In : a2In;
    const float* gIn    = sh ? g1 : g2;
    const float* bIn    = sh ? b1 : b2;
    const ushort_t* Wt  = sh ? W1 : W2;
    ushort_t* Y         = sh ? Y1o : Y2o;
    float* accOut       = sh ? a1Out : a2Out;
    const int ldY       = sh ? 256 : 128;
    const int bnh       = sh ? 2 : 1;
    const int fid       = sh ? blockIdx.x : blockIdx.x - 2200;
    const int nblocks   = sh ? 2200 : 1100;
    const int sqoff     = ldY;

    __shared__ ushort_t Asm[2][128 * 64];
    __shared__ ushort_t Bsm[2][128 * 64];
    __shared__ float parS[512];
    const int tid  = threadIdx.x;
    const int w    = tid >> 6;
    const int lane = tid & 63;
    {
        float m = accIn[tid] * INV_S;
        float v = accIn[256 + tid] * INV_S - m * m;
        float sc = gIn[tid] * rsqrtf(v + EPS);
        parS[tid] = sc;
        parS[256 + tid] = bIn[tid] - m * sc;
    }
    __syncthreads();

    const int virt = xcd_virt(fid, nblocks);
    const int pi   = virt / bnh;
    const int bn   = (virt % bnh) * 128;
    const int bm   = pi * 128;
    const int wr   = (w >> 1) * 64;
    const int wc   = (w & 1) * 64;

    const int qlog = (lane & 7) ^ ((8 * w + (lane >> 3)) & 7);
    size_t aoff[4]; size_t boff[4]; int arow[4];
#pragma unroll
    for (int j = 0; j < 4; ++j) {
        int row  = 32 * j + 8 * w + (lane >> 3);
        arow[j] = row;
        aoff[j] = (size_t)(bm + row) * 256 + qlog * 8;
        boff[j] = (size_t)(bn + row) * 256 + qlog * 8;
    }
    const int lo = (w * 8) * 64;
    const int lsub = (lane & 7) * 8;

    bf16x8 ar[2][4];
#pragma unroll
    for (int j = 0; j < 4; ++j) async16(Wt + boff[j], &Bsm[0][(j * 32) * 64 + lo]);
#pragma unroll
    for (int j = 0; j < 4; ++j) ar[0][j] = *(const bf16x8*)(X + aoff[j]);
    {
        const int cb = qlog * 8;
#pragma unroll
        for (int j = 0; j < 4; ++j)
            *(bf16x8*)&Asm[0][arow[j] * 64 + lsub] =
                bnrelu8(ar[0][j], parS + cb, parS + 256 + cb);
    }
    wait_lgkm0();

    f32x4 acc[4][4] = {};
#pragma unroll
    for (int kc = 0; kc < 4; ++kc) {
        if (kc < 3) {
#pragma unroll
            for (int j = 0; j < 4; ++j)
                async16(Wt + boff[j] + (kc + 1) * 64, &Bsm[(kc + 1) & 1][(j * 32) * 64 + lo]);
#pragma unroll
            for (int j = 0; j < 4; ++j)
                ar[(kc + 1) & 1][j] = *(const bf16x8*)(X + aoff[j] + (kc + 1) * 64);
            wait_vmcnt8();
        } else {
            wait_vmcnt0();
        }
        __builtin_amdgcn_s_barrier();
        const ushort_t* Ac = Asm[kc & 1];
        const ushort_t* Bc = Bsm[kc & 1];
        __builtin_amdgcn_s_setprio(1);
#pragma unroll
        for (int ks = 0; ks < 2; ++ks) {
            const int q = ks * 4 + (lane >> 4);
            bf16x8 af[4], bfr[4];
#pragma unroll
            for (int i = 0; i < 4; ++i) {
                int ra = wr + i * 16 + (lane & 15);
                af[i] = *(const bf16x8*)&Ac[ra * 64 + ((q ^ (ra & 7)) * 8)];
            }
#pragma unroll
            for (int jn = 0; jn < 4; ++jn) {
                int rn = wc + jn * 16 + (lane & 15);
                bfr[jn] = *(const bf16x8*)&Bc[rn * 64 + ((q ^ (rn & 7)) * 8)];
            }
#pragma unroll
            for (int i = 0; i < 4; ++i)
#pragma unroll
                for (int jn = 0; jn < 4; ++jn)
                    acc[i][jn] = __builtin_amdgcn_mfma_f32_16x16x32_bf16(
                        af[i], bfr[jn], acc[i][jn], 0, 0, 0);
        }
        __builtin_amdgcn_s_setprio(0);
        if (kc < 3) {
            const int cb = (kc + 1) * 64 + qlog * 8;
#pragma unroll
            for (int j = 0; j < 4; ++j)
                *(bf16x8*)&Asm[(kc + 1) & 1][arow[j] * 64 + lsub] =
                    bnrelu8(ar[(kc + 1) & 1][j], parS + cb, parS + 256 + cb);
            wait_lgkm0();
        }
        memfence_compiler();
        __builtin_amdgcn_s_barrier();
    }
    __syncthreads();

    const int crow0 = bm + wr + (lane >> 4) * 4;
    const int ccol0 = bn + wc + (lane & 15);
    float ls[4] = {}, lq[4] = {};
#pragma unroll
    for (int i = 0; i < 4; ++i)
#pragma unroll
        for (int jn = 0; jn < 4; ++jn) {
            int col = ccol0 + jn * 16;
#pragma unroll
            for (int r = 0; r < 4; ++r) {
                float v = acc[i][jn][r];
                ls[jn] += v; lq[jn] += v * v;
                Y[(size_t)(crow0 + i * 16 + r) * ldY + col] = f2bf(v);
            }
        }
#pragma unroll
    for (int jn = 0; jn < 4; ++jn) {
        ls[jn] += __shfl_xor(ls[jn], 16, 64); ls[jn] += __shfl_xor(ls[jn], 32, 64);
        lq[jn] += __shfl_xor(lq[jn], 16, 64); lq[jn] += __shfl_xor(lq[jn], 32, 64);
    }
    float* red = (float*)&Asm[0][0];
    if (lane < 16) {
#pragma unroll
        for (int jn = 0; jn < 4; ++jn) {
            red[((w * 16 + lane) * 4 + jn) * 2 + 0] = ls[jn];
            red[((w * 16 + lane) * 4 + jn) * 2 + 1] = lq[jn];
        }
    }
    __syncthreads();
    if (tid < 256) {
        int colhalf = tid & 127, isq = tid >> 7;
        int pair = colhalf >> 6, within = colhalf & 63;
        int l16 = within & 15, jn = within >> 4;
        int w0 = pair ? 1 : 0, w1 = pair ? 3 : 2;
        float s = red[((w0 * 16 + l16) * 4 + jn) * 2 + isq]
                + red[((w1 * 16 + l16) * 4 + jn) * 2 + isq];
        atomicAdd(&accOut[(bn + colhalf) + isq * sqoff], s);
    }
}

// ---------------------------------------------------------------- conv1 ------
// R8-proven reg-staged structure; transform = row-scalar multiply by FAC[s].
// __launch_bounds__(256,4) caps VGPR at 128 — R11 measured 132 VGPR, which
// crossed the 128 occupancy cliff (m69) and halved resident blocks (20.8->11.2%).
__global__ __launch_bounds__(256, 4) void k_convmma_fac(
    const ushort_t* __restrict__ X, const float* __restrict__ FAC,
    const ushort_t* __restrict__ Wt,
    ushort_t* __restrict__ Yb, const float* __restrict__ bias,
    const ushort_t* __restrict__ zp, float* __restrict__ accp)
{
    __shared__ ushort_t Asm[2][192 * 64];
    __shared__ ushort_t Bsm[2][128 * 64];
    const int tid  = threadIdx.x;
    const int w    = tid >> 6;
    const int lane = tid & 63;
    const int virt = xcd_virt(blockIdx.x, 2200);
    const int pi   = virt >> 1;
    const int bn   = (virt & 1) * 128;
    const int b    = pi / 275;
    const int rem  = pi % 275;
    const int th   = rem / 11, tw = rem % 11;
    const int y0   = th * 8 - 1, x0 = tw * 16 - 1;
    const int hb   = (w >> 1) * 4;
    const int wc   = (w & 1) * 64;

    const int qlog = (lane & 7) ^ (lane >> 3);
    const ushort_t* asrc[6];
    bool okj[6];
    int arow[6];
    float fj[6];
#pragma unroll
    for (int j = 0; j < 6; ++j) {
        int hr = j * 32 + w * 8 + (lane >> 3);
        arow[j] = hr;
        int ph = hr / 18, pw = hr % 18;
        int y = y0 + ph, x = x0 + pw;
        okj[j] = (hr < 180) && ((unsigned)y < (unsigned)H_DIM) &&
                 ((unsigned)x < (unsigned)W_DIM);
        size_t s = (size_t)b * HW + (size_t)y * W_DIM + x;
        asrc[j] = okj[j] ? X + s * 256 + qlog * 8 : zp + (lane & 7) * 8;
        fj[j] = okj[j] ? FAC[s] : 0.f;
    }
    const ushort_t* bsrc = Wt + (size_t)(bn + w * 8 + (lane >> 3)) * 256 + qlog * 8;
    const int lo = (w * 8) * 64;
    const int lsub = (lane & 7) * 8;
    const bf16x8 zv = 0;

    bf16x8 areg[6];
#pragma unroll
    for (int j = 0; j < 6; ++j) areg[j] = *(const bf16x8*)(asrc[j]);
#pragma unroll
    for (int j = 0; j < 4; ++j)
        async16(bsrc + (size_t)j * 8192, &Bsm[0][(j * 32) * 64 + lo]);
    {
#pragma unroll
        for (int j = 0; j < 6; ++j)
            *(bf16x8*)&Asm[0][arow[j] * 64 + lsub] =
                okj[j] ? mul8(areg[j], fj[j]) : zv;
    }
    wait_lgkm0();

    f32x4 acc[4][4] = {};
#pragma unroll
    for (int kc = 0; kc < 4; ++kc) {
        const ushort_t* acur = Asm[kc & 1];
#pragma unroll
        for (int pos = 0; pos < 9; ++pos) {
            const ushort_t* bcur = Bsm[(kc + pos) & 1];
            ushort_t* bnxt = (ushort_t*)Bsm[(kc + pos + 1) & 1];
            if (pos < 8) {
#pragma unroll
                for (int j = 0; j < 4; ++j)
                    async16(bsrc + (size_t)(pos + 1) * 65536 + kc * 64 + j * 8192,
                            bnxt + (j * 32) * 64 + lo);
            } else if (kc < 3) {
#pragma unroll
                for (int j = 0; j < 4; ++j)
                    async16(bsrc + (size_t)(kc + 1) * 64 + j * 8192,
                            bnxt + (j * 32) * 64 + lo);
            }
            if (pos == 5 && kc < 3) {
#pragma unroll
                for (int j = 0; j < 6; ++j)
                    areg[j] = *(const bf16x8*)(asrc[j] + (kc + 1) * 64);
            }
            if (kc == 3 && pos == 8)      wait_vmcnt0();
            else if (pos == 6 && kc < 3)  wait_vmcnt10();
            else                          wait_vmcnt4();
            __builtin_amdgcn_s_barrier();
            const int dy = pos / 3 - 1, dx = pos % 3 - 1;
            __builtin_amdgcn_s_setprio(1);
#pragma unroll
            for (int ks = 0; ks < 2; ++ks) {
                const int q = ks * 4 + (lane >> 4);
                bf16x8 af[4], bfr[4];
#pragma unroll
                for (int i = 0; i < 4; ++i) {
                    int ri = (hb + i + 1 + dy) * 18 + 1 + dx + (lane & 15);
                    af[i] = *(const bf16x8*)&acur[ri * 64 + ((q ^ (ri & 7)) * 8)];
                }
#pragma unroll
                for (int jn = 0; jn < 4; ++jn) {
                    int rn = wc + jn * 16 + (lane & 15);
                    bfr[jn] = *(const bf16x8*)&bcur[rn * 64 + ((q ^ (rn & 7)) * 8)];
                }
#pragma unroll
                for (int i = 0; i < 4; ++i)
#pragma unroll
                    for (int jn = 0; jn < 4; ++jn)
                        acc[i][jn] = __builtin_amdgcn_mfma_f32_16x16x32_bf16(
                            af[i], bfr[jn], acc[i][jn], 0, 0, 0);
            }
            __builtin_amdgcn_s_setprio(0);
            if (pos == 8 && kc < 3) {
#pragma unroll
                for (int j = 0; j < 6; ++j)
                    *(bf16x8*)&Asm[(kc + 1) & 1][arow[j] * 64 + lsub] =
                        okj[j] ? mul8(areg[j], fj[j]) : zv;
                wait_lgkm0();
            }
            memfence_compiler();
            __builtin_amdgcn_s_barrier();
        }
    }
    __syncthreads();

    const size_t sbase = (size_t)b * HW + (size_t)(th * 8) * W_DIM + tw * 16;
    const int colb = bn + wc + (lane & 15);
    const int wsub = (lane >> 4) * 4;
    float ls[4] = {}, lq[4] = {};
#pragma unroll
    for (int i = 0; i < 4; ++i) {
        int h = hb + i;
#pragma unroll
        for (int jn = 0; jn < 4; ++jn) {
            int col = colb + jn * 16;
            float bb = bias ? bias[col] : 0.f;
#pragma unroll
            for (int r = 0; r < 4; ++r) {
                size_t s = sbase + (size_t)h * W_DIM + wsub + r;
                float v = acc[i][jn][r] + bb;
                ls[jn] += v; lq[jn] += v * v;
                Yb[s * 256 + col] = f2bf(v);
            }
        }
    }
#pragma unroll
    for (int jn = 0; jn < 4; ++jn) {
        ls[jn] += __shfl_xor(ls[jn], 16, 64); ls[jn] += __shfl_xor(ls[jn], 32, 64);
        lq[jn] += __shfl_xor(lq[jn], 16, 64); lq[jn] += __shfl_xor(lq[jn], 32, 64);
    }
    float* red = (float*)&Asm[0][0];
    if (lane < 16) {
#pragma unroll
        for (int jn = 0; jn < 4; ++jn) {
            red[((w * 16 + lane) * 4 + jn) * 2 + 0] = ls[jn];
            red[((w * 16 + lane) * 4 + jn) * 2 + 1] = lq[jn];
        }
    }
    __syncthreads();
    if (tid < 256) {
        int colhalf = tid & 127, isq = tid >> 7;
        int pair = colhalf >> 6, within = colhalf & 63;
        int l16 = within & 15, jn = within >> 4;
        int w0 = pair ? 1 : 0, w1 = pair ? 3 : 2;
        float s = red[((w0 * 16 + l16) * 4 + jn) * 2 + isq]
                + red[((w1 * 16 + l16) * 4 + jn) * 2 + isq];
        atomicAdd(&accp[(bn + colhalf) + isq * 256], s);
    }
}

// conv2: proven R8 kernel — BN-fused reg-staged halo (8h x 16w patches)
__global__ __launch_bounds__(256) void k_convmma_bn(
    const ushort_t* __restrict__ X, const float* __restrict__ par,
    const ushort_t* __restrict__ Wt,
    ushort_t* __restrict__ Yb, const float* __restrict__ bias,
    const ushort_t* __restrict__ zp, float* __restrict__ accp)
{
    __shared__ ushort_t Asm[2][192 * 64];
    __shared__ ushort_t Bsm[2][128 * 64];
    const int tid  = threadIdx.x;
    const int w    = tid >> 6;
    const int lane = tid & 63;
    const int virt = xcd_virt(blockIdx.x, 2200);
    const int pi   = virt >> 1;
    const int bn   = (virt & 1) * 128;
    const int b    = pi / 275;
    const int rem  = pi % 275;
    const int th   = rem / 11, tw = rem % 11;
    const int y0   = th * 8 - 1, x0 = tw * 16 - 1;
    const int hb   = (w >> 1) * 4;
    const int wc   = (w & 1) * 64;

    const int qlog = (lane & 7) ^ (lane >> 3);
    const ushort_t* asrc[6];
    bool okj[6];
    int arow[6];
#pragma unroll
    for (int j = 0; j < 6; ++j) {
        int hr = j * 32 + w * 8 + (lane >> 3);
        arow[j] = hr;
        int ph = hr / 18, pw = hr % 18;
        int y = y0 + ph, x = x0 + pw;
        okj[j] = (hr < 180) && ((unsigned)y < (unsigned)H_DIM) &&
                 ((unsigned)x < (unsigned)W_DIM);
        asrc[j] = okj[j] ? X + ((size_t)b * HW + (size_t)y * W_DIM + x) * 256 + qlog * 8
                         : zp + (lane & 7) * 8;
    }
    const ushort_t* bsrc = Wt + (size_t)(bn + w * 8 + (lane >> 3)) * 256 + qlog * 8;
    const int lo = (w * 8) * 64;
    const int lsub = (lane & 7) * 8;
    const bf16x8 zv = 0;

    bf16x8 areg[6];
#pragma unroll
    for (int j = 0; j < 6; ++j) areg[j] = *(const bf16x8*)(asrc[j]);
#pragma unroll
    for (int j = 0; j < 4; ++j)
        async16(bsrc + (size_t)j * 8192, &Bsm[0][(j * 32) * 64 + lo]);
    {
        const int cb = qlog * 8;
#pragma unroll
        for (int j = 0; j < 6; ++j)
            *(bf16x8*)&Asm[0][arow[j] * 64 + lsub] =
                okj[j] ? bnrelu8(areg[j], par + cb, par + 256 + cb) : zv;
    }
    wait_lgkm0();

    f32x4 acc[4][4] = {};
#pragma unroll
    for (int kc = 0; kc < 4; ++kc) {
        const ushort_t* acur = Asm[kc & 1];
#pragma unroll
        for (int pos = 0; pos < 9; ++pos) {
            const ushort_t* bcur = Bsm[(kc + pos) & 1];
            ushort_t* bnxt = (ushort_t*)Bsm[(kc + pos + 1) & 1];
            if (pos < 8) {
#pragma unroll
                for (int j = 0; j < 4; ++j)
                    async16(bsrc + (size_t)(pos + 1) * 65536 + kc * 64 + j * 8192,
                            bnxt + (j * 32) * 64 + lo);
            } else if (kc < 3) {
#pragma unroll
                for (int j = 0; j < 4; ++j)
                    async16(bsrc + (size_t)(kc + 1) * 64 + j * 8192,
                            bnxt + (j * 32) * 64 + lo);
            }
            if (pos == 5 && kc < 3) {
#pragma unroll
                for (int j = 0; j < 6; ++j)
                    areg[j] = *(const bf16x8*)(asrc[j] + (kc + 1) * 64);
            }
            if (kc == 3 && pos == 8)      wait_vmcnt0();
            else if (pos == 6 && kc < 3)  wait_vmcnt10();
            else                          wait_vmcnt4();
            __builtin_amdgcn_s_barrier();
            const int dy = pos / 3 - 1, dx = pos % 3 - 1;
            __builtin_amdgcn_s_setprio(1);
#pragma unroll
            for (int ks = 0; ks < 2; ++ks) {
                const int q = ks * 4 + (lane >> 4);
                bf16x8 af[4], bfr[4];
#pragma unroll
                for (int i = 0; i < 4; ++i) {
                    int ri = (hb + i + 1 + dy) * 18 + 1 + dx + (lane & 15);
                    af[i] = *(const bf16x8*)&acur[ri * 64 + ((q ^ (ri & 7)) * 8)];
                }
#pragma unroll
                for (int jn = 0; jn < 4; ++jn) {
                    int rn = wc + jn * 16 + (lane & 15);
                    bfr[jn] = *(const bf16x8*)&bcur[rn * 64 + ((q ^ (rn & 7)) * 8)];
                }
#pragma unroll
                for (int i = 0; i < 4; ++i)
#pragma unroll
                    for (int jn = 0; jn < 4; ++jn)
                        acc[i][jn] = __builtin_amdgcn_mfma_f32_16x16x32_bf16(
                            af[i], bfr[jn], acc[i][jn], 0, 0, 0);
            }
            __builtin_amdgcn_s_setprio(0);
            if (pos == 8 && kc < 3) {
                const int cb = (kc + 1) * 64 + qlog * 8;
#pragma unroll
                for (int j = 0; j < 6; ++j)
                    *(bf16x8*)&Asm[(kc + 1) & 1][arow[j] * 64 + lsub] =
                        okj[j] ? bnrelu8(areg[j], par + cb, par + 256 + cb) : zv;
                wait_lgkm0();
            }
            memfence_compiler();
            __builtin_amdgcn_s_barrier();
        }
    }
    __syncthreads();

    const size_t sbase = (size_t)b * HW + (size_t)(th * 8) * W_DIM + tw * 16;
    const int colb = bn + wc + (lane & 15);
    const int wsub = (lane >> 4) * 4;
    float ls[4] = {}, lq[4] = {};
#pragma unroll
    for (int i = 0; i < 4; ++i) {
        int h = hb + i;
#pragma unroll
        for (int jn = 0; jn < 4; ++jn) {
            int col = colb + jn * 16;
            float bb = bias ? bias[col] : 0.f;
#pragma unroll
            for (int r = 0; r < 4; ++r) {
                size_t s = sbase + (size_t)h * W_DIM + wsub + r;
                float v = acc[i][jn][r] + bb;
                ls[jn] += v; lq[jn] += v * v;
                Yb[s * 256 + col] = f2bf(v);
            }
        }
    }
#pragma unroll
    for (int jn = 0; jn < 4; ++jn) {
        ls[jn] += __shfl_xor(ls[jn], 16, 64); ls[jn] += __shfl_xor(ls[jn], 32, 64);
        lq[jn] += __shfl_xor(lq[jn], 16, 64); lq[jn] += __shfl_xor(lq[jn], 32, 64);
    }
    float* red = (float*)&Asm[0][0];
    if (lane < 16) {
#pragma unroll
        for (int jn = 0; jn < 4; ++jn) {
            red[((w * 16 + lane) * 4 + jn) * 2 + 0] = ls[jn];
            red[((w * 16 + lane) * 4 + jn) * 2 + 1] = lq[jn];
        }
    }
    __syncthreads();
    if (tid < 256) {
        int colhalf = tid & 127, isq = tid >> 7;
        int pair = colhalf >> 6, within = colhalf & 63;
        int l16 = within & 15, jn = within >> 4;
        int w0 = pair ? 1 : 0, w1 = pair ? 3 : 2;
        float s = red[((w0 * 16 + l16) * 4 + jn) * 2 + isq]
                + red[((w1 * 16 + l16) * 4 + jn) * 2 + isq];
        atomicAdd(&accp[(bn + colhalf) + isq * 256], s);
    }
}

// ------------------------------------------------- merged weight cast (1 launch)
__global__ __launch_bounds__(256) void k_castw_all(
    const float* __restrict__ cw1, const float* __restrict__ cw2,
    const float* __restrict__ shw1, const float* __restrict__ gw1,
    const float* __restrict__ shw2, const float* __restrict__ gw2,
    ushort_t* __restrict__ WT1, ushort_t* __restrict__ WT2,
    ushort_t* __restrict__ WCAT, ushort_t* __restrict__ WS2,
    ushort_t* __restrict__ WG2)
{
    const int bid = blockIdx.x, ci = threadIdx.x;
    const float* src; ushort_t* dst; int CO, pc;
    if (bid < 2304)      { src = cw1;  dst = WT1;          CO = 256; pc = bid; }
    else if (bid < 4608) { src = cw2;  dst = WT2;          CO = 256; pc = bid - 2304; }
    else if (bid < 4864) { src = shw1; dst = WCAT;         CO = 256; pc = bid - 4608; }
    else if (bid < 5120) { src = gw1;  dst = WCAT + 65536; CO = 256; pc = bid - 4864; }
    else if (bid < 5376) { src = shw2; dst = WS2;          CO = 256; pc = bid - 5120; }
    else                 { src = gw2;  dst = WG2;          CO = 128; pc = bid - 5376; }
    int co = pc % CO, pos = pc / CO;
    dst[(size_t)pc * 256 + ci] = f2bf(src[((size_t)pos * 256 + ci) * CO + co]);
}

// ---------------------------------------------------------------- BN params --
__global__ void k_bnparams(const float* __restrict__ acc,
                           const float* __restrict__ g,
                           const float* __restrict__ b,
                           float* __restrict__ par, int ncols)
{
    int c = threadIdx.x;
    if (c >= ncols) return;
    float m = acc[c] * INV_S;
    float v = acc[ncols + c] * INV_S - m * m;
    float sc = g[c] * rsqrtf(v + EPS);
    par[c] = sc;
    par[ncols + c] = b[c] - m * sc;
}

// ---------------------------------------------------------------- head -------
// lite: computes only factor[s] = shdc * gaus -> FAC (f32)
__global__ __launch_bounds__(256) void k_headfin_fac(
    const ushort_t* __restrict__ B2, const ushort_t* __restrict__ B3,
    const float* __restrict__ acc1, const float* __restrict__ shg2,
    const float* __restrict__ shb2,
    const float* __restrict__ acc3, const float* __restrict__ gg2,
    const float* __restrict__ gb2,
    const float* __restrict__ shw3, const float* __restrict__ shb3,
    const float* __restrict__ gw3, const float* __restrict__ gb3,
    float* __restrict__ FAC)
{
    __shared__ float parA[512], parB[256];
    const int t = threadIdx.x;
    {
        float m = acc1[t] * INV_S;
        float v = acc1[256 + t] * INV_S - m * m;
        float sc = shg2[t] * rsqrtf(v + EPS);
        parA[t] = sc; parA[256 + t] = shb2[t] - m * sc;
    }
    if (t < 128) {
        float m = acc3[t] * INV_S;
        float v = acc3[128 + t] * INV_S - m * m;
        float sc = gg2[t] * rsqrtf(v + EPS);
        parB[t] = sc; parB[128 + t] = gb2[t] - m * sc;
    }
    __syncthreads();

    const int wave = t >> 6;
    const int lane = t & 63;
    const int s = blockIdx.x * 4 + wave;
    const ushort_t* b2 = B2 + (size_t)s * 256;
    const ushort_t* b3 = B3 + (size_t)s * 128;
    float d1 = 0.f, d2 = 0.f;
    {
        ushort4 u = ((const ushort4*)b2)[lane];
        int c = lane * 4;
        float v0 = fmaxf(0.f, bf2f(u.x) * parA[c + 0] + parA[256 + c + 0]);
        float v1 = fmaxf(0.f, bf2f(u.y) * parA[c + 1] + parA[256 + c + 1]);
        float v2 = fmaxf(0.f, bf2f(u.z) * parA[c + 2] + parA[256 + c + 2]);
        float v3 = fmaxf(0.f, bf2f(u.w) * parA[c + 3] + parA[256 + c + 3]);
        d1 = v0 * shw3[(c + 0) * 9] + v1 * shw3[(c + 1) * 9]
           + v2 * shw3[(c + 2) * 9] + v3 * shw3[(c + 3) * 9];
    }
    {
        ushort2 u = ((const ushort2*)b3)[lane];
        int c = lane * 2;
        float v0 = fmaxf(0.f, bf2f(u.x) * parB[c + 0] + parB[128 + c + 0]);
        float v1 = fmaxf(0.f, bf2f(u.y) * parB[c + 1] + parB[128 + c + 1]);
        d2 = v0 * gw3[c + 0] + v1 * gw3[c + 1];
    }
#pragma unroll
    for (int off = 32; off > 0; off >>= 1) {
        d1 += __shfl_down(d1, off, 64);
        d2 += __shfl_down(d2, off, 64);
    }
    if (lane == 0) {
        float shdc = d1 + shb3[0];
        float gaus = 1.f / (1.f + expf(-(d2 + gb3[0])));
        FAC[s] = shdc * gaus;
    }
}

// ---------------------------------------------------------------- final ------
__global__ __launch_bounds__(256) void k_bnrelu_f32out(
    const ushort_t* __restrict__ Y, const float* __restrict__ acc5,
    const float* __restrict__ g, const float* __restrict__ b,
    float* __restrict__ out)
{
    __shared__ float par[512];
    const int t = threadIdx.x;
    {
        float m = acc5[t] * INV_S;
        float v = acc5[256 + t] * INV_S - m * m;
        float sc = g[t] * rsqrtf(v + EPS);
        par[t] = sc; par[256 + t] = b[t] - m * sc;
    }
    __syncthreads();
    size_t q = (size_t)blockIdx.x * 256 + t;
    int c = (int)(q & 63) * 4;
    ushort4 u = ((const ushort4*)Y)[q];
    float4 v;
    v.x = fmaxf(0.f, bf2f(u.x) * par[c + 0] + par[256 + c + 0]);
    v.y = fmaxf(0.f, bf2f(u.y) * par[c + 1] + par[256 + c + 1]);
    v.z = fmaxf(0.f, bf2f(u.z) * par[c + 2] + par[256 + c + 2]);
    v.w = fmaxf(0.f, bf2f(u.w) * par[c + 3] + par[256 + c + 3]);
    ((float4*)out)[q] = v;
}

// ---------------------------------------------------------------- launch -----
extern "C" void kernel_launch(void* const* d_in, const int* in_sizes, int n_in,
                              void* d_out, int out_size, void* d_ws, size_t ws_size,
                              hipStream_t stream)
{
    (void)in_sizes; (void)n_in; (void)out_size; (void)ws_size;
    const float* feats   = (const float*)d_in[0];
    const int*   cb      = (const int*)d_in[1];
    const int*   cy      = (const int*)d_in[2];
    const int*   cx      = (const int*)d_in[3];
    const float* sh_w1   = (const float*)d_in[4];
    const float* sh_g1   = (const float*)d_in[5];
    const float* sh_b1   = (const float*)d_in[6];
    const float* sh_w2   = (const float*)d_in[7];
    const float* sh_g2   = (const float*)d_in[8];
    const float* sh_b2   = (const float*)d_in[9];
    const float* sh_w3   = (const float*)d_in[10];
    const float* sh_bias3= (const float*)d_in[11];
    const float* g_w1    = (const float*)d_in[12];
    const float* g_g1    = (const float*)d_in[13];
    const float* g_b1    = (const float*)d_in[14];
    const float* g_w2    = (const float*)d_in[15];
    const float* g_g2    = (const float*)d_in[16];
    const float* g_b2    = (const float*)d_in[17];
    const float* g_w3    = (const float*)d_in[18];
    const float* g_bias3 = (const float*)d_in[19];
    const float* cw1     = (const float*)d_in[20];
    const float* c1_g    = (const float*)d_in[21];
    const float* c1_b    = (const float*)d_in[22];
    const float* cw2     = (const float*)d_in[23];
    const float* c2_bias = (const float*)d_in[24];
    const float* c2_g    = (const float*)d_in[25];
    const float* c2_b    = (const float*)d_in[26];

    float* out = (float*)d_out;
    float* ws  = (float*)d_ws;
    ushort_t* Pb   = (ushort_t*)(ws);                    // pooled bf16 [S][256] (live thru conv1)
    ushort_t* Bsh  = (ushort_t*)(ws + 18022400);         // SH1 raw -> conv1 out
    ushort_t* Bg   = (ushort_t*)(ws + 36044800);         // G1 raw
    ushort_t* Cb   = (ushort_t*)(ws + 54067200);         // SH2 raw -> conv2 out
    ushort_t* FT   = (ushort_t*)(ws + 54067200);         // alias (pool phase)
    ushort_t* Db   = (ushort_t*)(ws + 72089600);         // G2 raw [S][128]
    int*      CNTi = (int*)(ws + 72089600);              // alias (pool phase)
    int*      PSL  = CNTi + S_TOT;
    int*      VID  = PSL + S_TOT * 8;
    ushort_t* WCAT = (ushort_t*)(ws + 81100800);         // [512][256] layer-1
    ushort_t* WS2  = WCAT + 131072;
    ushort_t* WG2  = WS2 + 65536;                        // [128][256]
    ushort_t* WT1  = WG2 + 32768;                        // 9*256*256
    ushort_t* WT2  = WT1 + 589824;
    ushort_t* ZP   = WT2 + 589824;                       // 4KB zero page
    float*    ACC  = (float*)(ZP + 2048);                // 6 * 512
    float*    PAR  = ACC + 6 * 512;                      // conv1 BN params
    float*    FAC  = PAR + 512;                          // [S] f32 factor

    hipMemsetAsync(CNTi, 0, (size_t)S_TOT * 4, stream);
    hipMemsetAsync(ACC, 0, 6 * 512 * 4, stream);
    hipMemsetAsync(ZP, 0, 4096, stream);

    // weights -> bf16 [co][ci] (single merged launch)
    k_castw_all<<<5504, 256, 0, stream>>>(cw1, cw2, sh_w1, g_w1, sh_w2, g_w2,
                                          WT1, WT2, WCAT, WS2, WG2);

    // 1) pooling
    k_transpose<<<dim3(256, 4, 4), 256, 0, stream>>>(feats, FT);
    k_buildidx<<<NPTS / 256, 256, 0, stream>>>(cb, cy, cx, CNTi, PSL, VID);
    k_poolgather<<<S_TOT / 4, 256, 0, stream>>>(FT, CNTi, PSL, VID, Pb);

    // 2) merged layer-1 (SH1 | G1) raw outputs + stats
    k_gemmma<<<4400, 256, 0, stream>>>(Pb, WCAT, Bsh, Bg, 256, 4, 4400,
                                       ACC + 0 * 512, ACC + 2 * 512, 256);
    // 3+4) grouped SH-L2 (N=256) + G-L2 (N=128): bnrelu-on-the-fly + stats
    k_gemmma_bn2<<<3300, 256, 0, stream>>>(
        Bsh, ACC + 0 * 512, sh_g1, sh_b1, WS2, Cb, ACC + 1 * 512,
        Bg,  ACC + 2 * 512, g_g1,  g_b1,  WG2, Db, ACC + 3 * 512);
    // 5) head finalize lite: FAC[s] only
    k_headfin_fac<<<S_TOT / 4, 256, 0, stream>>>(Cb, Db,
                                                 ACC + 1 * 512, sh_g2, sh_b2,
                                                 ACC + 3 * 512, g_g2, g_b2,
                                                 sh_w3, sh_bias3, g_w3, g_bias3,
                                                 FAC);
    // 6) conv1 (reg-staged, factor-on-the-fly, VGPR<=128): Bsh = conv3x3(Pb*FAC)
    k_convmma_fac<<<2200, 256, 0, stream>>>(Pb, FAC, WT1, Bsh, nullptr, ZP,
                                            ACC + 4 * 512);
    k_bnparams<<<1, 256, 0, stream>>>(ACC + 4 * 512, c1_g, c1_b, PAR, 256);
    // 7) conv2 (proven R8 BN-fused): Cb = conv3x3(bnrelu(Bsh)) + bias + stats
    k_convmma_bn<<<2200, 256, 0, stream>>>(Bsh, PAR, WT2, Cb, c2_bias, ZP,
                                           ACC + 5 * 512);
    // 8) final BN+ReLU -> f32 out (in-kernel params)
    k_bnrelu_f32out<<<35200, 256, 0, stream>>>(Cb, ACC + 5 * 512, c2_g, c2_b, out);
}

// Round 13
// 717.515 us; speedup vs baseline: 1.0888x; 1.0888x over previous
//
#include <hip/hip_runtime.h>
#include <hip/hip_bf16.h>
#include <cstdint>
#include <cstddef>

// Problem constants
#define B_DIM 4
#define H_DIM 200
#define W_DIM 176
#define CCH 256
#define NPP 16384        // points per batch entry (N)
#define NPTS 65536       // total points (P)
#define HW 35200         // H*W
#define S_TOT 140800     // B*H*W
#define EPS 1e-3f
#define INV_S (1.0f/140800.0f)

typedef unsigned short ushort_t;
typedef __attribute__((ext_vector_type(8))) short bf16x8;
typedef __attribute__((ext_vector_type(4))) float f32x4;

__device__ __forceinline__ ushort_t f2bf(float f) {
    __hip_bfloat16 h = __float2bfloat16(f);   // RNE
    return *(ushort_t*)&h;
}
__device__ __forceinline__ float bf2f(ushort_t u) {
    __hip_bfloat16 h = *(__hip_bfloat16*)&u;
    return __bfloat162float(h);
}

__device__ __forceinline__ void async16(const void* g, void* l) {
    __builtin_amdgcn_global_load_lds(
        (const __attribute__((address_space(1))) unsigned int*)g,
        (__attribute__((address_space(3))) unsigned int*)l,
        16, 0, 0);
}

// counted waits (T4)
__device__ __forceinline__ void wait_vmcnt0()  { asm volatile("s_waitcnt vmcnt(0)" ::: "memory"); }
__device__ __forceinline__ void wait_vmcnt4()  { asm volatile("s_waitcnt vmcnt(4)" ::: "memory"); }
__device__ __forceinline__ void wait_vmcnt8()  { asm volatile("s_waitcnt vmcnt(8)" ::: "memory"); }
__device__ __forceinline__ void wait_vmcnt10() { asm volatile("s_waitcnt vmcnt(10)" ::: "memory"); }
__device__ __forceinline__ void wait_lgkm0()   { asm volatile("s_waitcnt lgkmcnt(0)" ::: "memory"); }
__device__ __forceinline__ void memfence_compiler() { asm volatile("" ::: "memory"); }

// BN+ReLU on 8 packed bf16 (sc/sh pre-offset to the channel base)
__device__ __forceinline__ bf16x8 bnrelu8(bf16x8 a, const float* __restrict__ sc,
                                          const float* __restrict__ sh) {
    bf16x8 r;
#pragma unroll
    for (int e = 0; e < 8; ++e) {
        float f = bf2f((ushort_t)a[e]);
        r[e] = (short)f2bf(fmaxf(0.f, f * sc[e] + sh[e]));
    }
    return r;
}

// bijective XCD swizzle (m204)
__device__ __forceinline__ int xcd_virt(int fid, int n) {
    int q = n >> 3, r = n & 7;
    int xcd = fid & 7, idx = fid >> 3;
    int base = (xcd < r) ? xcd * (q + 1) : r * (q + 1) + (xcd - r) * q;
    return base + idx;
}

// ---------------------------------------------------------------- transpose --
__global__ __launch_bounds__(256) void k_transpose(
    const float* __restrict__ feats, ushort_t* __restrict__ FT)
{
    __shared__ float lds[64][65];
    const int b  = blockIdx.z;
    const int c0 = blockIdx.y * 64;
    const int n0 = blockIdx.x * 64;
    const int tid = threadIdx.x;
#pragma unroll
    for (int i = 0; i < 16; ++i) {
        int idx = i * 256 + tid;
        int cr = idx >> 6, nc = idx & 63;
        lds[cr][nc] = feats[((size_t)b * 256 + c0 + cr) * NPP + n0 + nc];
    }
    __syncthreads();
#pragma unroll
    for (int i = 0; i < 16; ++i) {
        int idx = i * 256 + tid;
        int nr = idx >> 6, cc = idx & 63;
        FT[((size_t)b * NPP + n0 + nr) * CCH + c0 + cc] = f2bf(lds[cc][nr]);
    }
}

// ---------------------------------------------------------------- index build
__global__ __launch_bounds__(256) void k_buildidx(
    const int* __restrict__ cb, const int* __restrict__ cy,
    const int* __restrict__ cx, int* __restrict__ cnt,
    int* __restrict__ pslot, int* __restrict__ vid)
{
    int p = blockIdx.x * 256 + threadIdx.x;
    int v = cb[p] * HW + cy[p] * W_DIM + cx[p];
    vid[p] = v;
    int r = atomicAdd(&cnt[v], 1);
    if (r < 8) pslot[v * 8 + r] = p;
}

// ---------------------------------------------------------------- pool gather
__global__ __launch_bounds__(256) void k_poolgather(
    const ushort_t* __restrict__ FT, const int* __restrict__ cnt,
    const int* __restrict__ pslot, const int* __restrict__ vid,
    ushort_t* __restrict__ Pb)
{
    const int wave = threadIdx.x >> 6;
    const int lane = threadIdx.x & 63;
    const int v = blockIdx.x * 4 + wave;
    const int c = cnt[v];
    float a0 = 0.f, a1 = 0.f, a2 = 0.f, a3 = 0.f;
    if (c <= 8) {
        for (int k = 0; k < c; ++k) {
            int p = pslot[v * 8 + k];
            ushort4 r = ((const ushort4*)(FT + (size_t)p * CCH))[lane];
            a0 += bf2f(r.x); a1 += bf2f(r.y); a2 += bf2f(r.z); a3 += bf2f(r.w);
        }
    } else {
        for (int p = 0; p < NPTS; ++p)
            if (vid[p] == v) {
                ushort4 r = ((const ushort4*)(FT + (size_t)p * CCH))[lane];
                a0 += bf2f(r.x); a1 += bf2f(r.y); a2 += bf2f(r.z); a3 += bf2f(r.w);
            }
    }
    float inv = c ? 1.f / (float)c : 0.f;
    ushort4 o;
    o.x = f2bf(a0 * inv); o.y = f2bf(a1 * inv);
    o.z = f2bf(a2 * inv); o.w = f2bf(a3 * inv);
    ((ushort4*)(Pb + (size_t)v * CCH))[lane] = o;
}

// ---------------------------------------------------------------- GEMM (L1) --
__global__ __launch_bounds__(256) void k_gemmma(
    const ushort_t* __restrict__ X, const ushort_t* __restrict__ Wt,
    ushort_t* __restrict__ Y1, ushort_t* __restrict__ Y2, int ldY,
    int bnh, int nblocks,
    float* __restrict__ acc0, float* __restrict__ acc1, int sqoff)
{
    __shared__ ushort_t Asm[2][128 * 64];
    __shared__ ushort_t Bsm[2][128 * 64];
    const int tid  = threadIdx.x;
    const int w    = tid >> 6;
    const int lane = tid & 63;
    const int virt = xcd_virt(blockIdx.x, nblocks);
    const int pi   = virt / bnh;
    const int bn   = (virt % bnh) * 128;
    const int bm   = pi * 128;
    const int wr   = (w >> 1) * 64;
    const int wc   = (w & 1) * 64;

    size_t aoff[4]; size_t boff[4];
#pragma unroll
    for (int j = 0; j < 4; ++j) {
        int row  = 32 * j + 8 * w + (lane >> 3);
        int qlog = (lane & 7) ^ (row & 7);
        aoff[j] = (size_t)(bm + row) * 256 + qlog * 8;
        boff[j] = (size_t)(bn + row) * 256 + qlog * 8;
    }
    const int lo = (w * 8) * 64;

#pragma unroll
    for (int j = 0; j < 4; ++j) async16(X + aoff[j], &Asm[0][(j * 32) * 64 + lo]);
#pragma unroll
    for (int j = 0; j < 4; ++j) async16(Wt + boff[j], &Bsm[0][(j * 32) * 64 + lo]);

    f32x4 acc[4][4] = {};
    for (int kc = 0; kc < 4; ++kc) {
        if (kc < 3) {
#pragma unroll
            for (int j = 0; j < 4; ++j)
                async16(X + aoff[j] + (kc + 1) * 64, &Asm[(kc + 1) & 1][(j * 32) * 64 + lo]);
#pragma unroll
            for (int j = 0; j < 4; ++j)
                async16(Wt + boff[j] + (kc + 1) * 64, &Bsm[(kc + 1) & 1][(j * 32) * 64 + lo]);
            wait_vmcnt8();
        } else {
            wait_vmcnt0();
        }
        __builtin_amdgcn_s_barrier();
        const ushort_t* Ac = Asm[kc & 1];
        const ushort_t* Bc = Bsm[kc & 1];
        __builtin_amdgcn_s_setprio(1);
#pragma unroll
        for (int ks = 0; ks < 2; ++ks) {
            const int q = ks * 4 + (lane >> 4);
            bf16x8 af[4], bfr[4];
#pragma unroll
            for (int i = 0; i < 4; ++i) {
                int ra = wr + i * 16 + (lane & 15);
                af[i] = *(const bf16x8*)&Ac[ra * 64 + ((q ^ (ra & 7)) * 8)];
            }
#pragma unroll
            for (int jn = 0; jn < 4; ++jn) {
                int rn = wc + jn * 16 + (lane & 15);
                bfr[jn] = *(const bf16x8*)&Bc[rn * 64 + ((q ^ (rn & 7)) * 8)];
            }
#pragma unroll
            for (int i = 0; i < 4; ++i)
#pragma unroll
                for (int jn = 0; jn < 4; ++jn)
                    acc[i][jn] = __builtin_amdgcn_mfma_f32_16x16x32_bf16(
                        af[i], bfr[jn], acc[i][jn], 0, 0, 0);
        }
        __builtin_amdgcn_s_setprio(0);
        memfence_compiler();
        __builtin_amdgcn_s_barrier();
    }
    __syncthreads();

    const int crow0 = bm + wr + (lane >> 4) * 4;
    const int ccol0 = bn + wc + (lane & 15);
    float ls[4] = {}, lq[4] = {};
#pragma unroll
    for (int i = 0; i < 4; ++i)
#pragma unroll
        for (int jn = 0; jn < 4; ++jn) {
            int col = ccol0 + jn * 16;
#pragma unroll
            for (int r = 0; r < 4; ++r) {
                float v = acc[i][jn][r];
                ls[jn] += v; lq[jn] += v * v;
                size_t row = (size_t)(crow0 + i * 16 + r);
                if (col < 256) Y1[row * ldY + col] = f2bf(v);
                else           Y2[row * ldY + col - 256] = f2bf(v);
            }
        }
#pragma unroll
    for (int jn = 0; jn < 4; ++jn) {
        ls[jn] += __shfl_xor(ls[jn], 16, 64); ls[jn] += __shfl_xor(ls[jn], 32, 64);
        lq[jn] += __shfl_xor(lq[jn], 16, 64); lq[jn] += __shfl_xor(lq[jn], 32, 64);
    }
    float* red = (float*)&Asm[0][0];
    if (lane < 16) {
#pragma unroll
        for (int jn = 0; jn < 4; ++jn) {
            red[((w * 16 + lane) * 4 + jn) * 2 + 0] = ls[jn];
            red[((w * 16 + lane) * 4 + jn) * 2 + 1] = lq[jn];
        }
    }
    __syncthreads();
    if (tid < 256) {
        int colhalf = tid & 127, isq = tid >> 7;
        int pair = colhalf >> 6, within = colhalf & 63;
        int l16 = within & 15, jn = within >> 4;
        int w0 = pair ? 1 : 0, w1 = pair ? 3 : 2;
        float s = red[((w0 * 16 + l16) * 4 + jn) * 2 + isq]
                + red[((w1 * 16 + l16) * 4 + jn) * 2 + isq];
        int colg = bn + colhalf;
        float* t = (colg < 256) ? acc0 : acc1;
        atomicAdd(&t[(colg & 255) + isq * sqoff], s);
    }
}

// ------------------------------------------------------- GEMM + BN (grouped) -
// blocks [0,2200): SH-L2 (N=256, bnh=2); blocks [2200,3300): G-L2 (N=128).
__global__ __launch_bounds__(256) void k_gemmma_bn2(
    const ushort_t* __restrict__ X1, const float* __restrict__ a1In,
    const float* __restrict__ g1, const float* __restrict__ b1,
    const ushort_t* __restrict__ W1, ushort_t* __restrict__ Y1o,
    float* __restrict__ a1Out,
    const ushort_t* __restrict__ X2, const float* __restrict__ a2In,
    const float* __restrict__ g2, const float* __restrict__ b2,
    const ushort_t* __restrict__ W2, ushort_t* __restrict__ Y2o,
    float* __restrict__ a2Out)
{
    const bool sh = blockIdx.x < 2200;
    const ushort_t* X   = sh ? X1 : X2;
    const float* accIn  = sh ? a1In : a2In;
    const float* gIn    = sh ? g1 : g2;
    const float* bIn    = sh ? b1 : b2;
    const ushort_t* Wt  = sh ? W1 : W2;
    ushort_t* Y         = sh ? Y1o : Y2o;
    float* accOut       = sh ? a1Out : a2Out;
    const int ldY       = sh ? 256 : 128;
    const int bnh       = sh ? 2 : 1;
    const int fid       = sh ? blockIdx.x : blockIdx.x - 2200;
    const int nblocks   = sh ? 2200 : 1100;
    const int sqoff     = ldY;

    __shared__ ushort_t Asm[2][128 * 64];
    __shared__ ushort_t Bsm[2][128 * 64];
    __shared__ float parS[512];
    const int tid  = threadIdx.x;
    const int w    = tid >> 6;
    const int lane = tid & 63;
    {
        float m = accIn[tid] * INV_S;
        float v = accIn[256 + tid] * INV_S - m * m;
        float sc = gIn[tid] * rsqrtf(v + EPS);
        parS[tid] = sc;
        parS[256 + tid] = bIn[tid] - m * sc;
    }
    __syncthreads();

    const int virt = xcd_virt(fid, nblocks);
    const int pi   = virt / bnh;
    const int bn   = (virt % bnh) * 128;
    const int bm   = pi * 128;
    const int wr   = (w >> 1) * 64;
    const int wc   = (w & 1) * 64;

    const int qlog = (lane & 7) ^ ((8 * w + (lane >> 3)) & 7);
    size_t aoff[4]; size_t boff[4]; int arow[4];
#pragma unroll
    for (int j = 0; j < 4; ++j) {
        int row  = 32 * j + 8 * w + (lane >> 3);
        arow[j] = row;
        aoff[j] = (size_t)(bm + row) * 256 + qlog * 8;
        boff[j] = (size_t)(bn + row) * 256 + qlog * 8;
    }
    const int lo = (w * 8) * 64;
    const int lsub = (lane & 7) * 8;

    bf16x8 ar[2][4];
#pragma unroll
    for (int j = 0; j < 4; ++j) async16(Wt + boff[j], &Bsm[0][(j * 32) * 64 + lo]);
#pragma unroll
    for (int j = 0; j < 4; ++j) ar[0][j] = *(const bf16x8*)(X + aoff[j]);
    {
        const int cb = qlog * 8;
#pragma unroll
        for (int j = 0; j < 4; ++j)
            *(bf16x8*)&Asm[0][arow[j] * 64 + lsub] =
                bnrelu8(ar[0][j], parS + cb, parS + 256 + cb);
    }
    wait_lgkm0();

    f32x4 acc[4][4] = {};
#pragma unroll
    for (int kc = 0; kc < 4; ++kc) {
        if (kc < 3) {
#pragma unroll
            for (int j = 0; j < 4; ++j)
                async16(Wt + boff[j] + (kc + 1) * 64, &Bsm[(kc + 1) & 1][(j * 32) * 64 + lo]);
#pragma unroll
            for (int j = 0; j < 4; ++j)
                ar[(kc + 1) & 1][j] = *(const bf16x8*)(X + aoff[j] + (kc + 1) * 64);
            wait_vmcnt8();
        } else {
            wait_vmcnt0();
        }
        __builtin_amdgcn_s_barrier();
        const ushort_t* Ac = Asm[kc & 1];
        const ushort_t* Bc = Bsm[kc & 1];
        __builtin_amdgcn_s_setprio(1);
#pragma unroll
        for (int ks = 0; ks < 2; ++ks) {
            const int q = ks * 4 + (lane >> 4);
            bf16x8 af[4], bfr[4];
#pragma unroll
            for (int i = 0; i < 4; ++i) {
                int ra = wr + i * 16 + (lane & 15);
                af[i] = *(const bf16x8*)&Ac[ra * 64 + ((q ^ (ra & 7)) * 8)];
            }
#pragma unroll
            for (int jn = 0; jn < 4; ++jn) {
                int rn = wc + jn * 16 + (lane & 15);
                bfr[jn] = *(const bf16x8*)&Bc[rn * 64 + ((q ^ (rn & 7)) * 8)];
            }
#pragma unroll
            for (int i = 0; i < 4; ++i)
#pragma unroll
                for (int jn = 0; jn < 4; ++jn)
                    acc[i][jn] = __builtin_amdgcn_mfma_f32_16x16x32_bf16(
                        af[i], bfr[jn], acc[i][jn], 0, 0, 0);
        }
        __builtin_amdgcn_s_setprio(0);
        if (kc < 3) {
            const int cb = (kc + 1) * 64 + qlog * 8;
#pragma unroll
            for (int j = 0; j < 4; ++j)
                *(bf16x8*)&Asm[(kc + 1) & 1][arow[j] * 64 + lsub] =
                    bnrelu8(ar[(kc + 1) & 1][j], parS + cb, parS + 256 + cb);
            wait_lgkm0();
        }
        memfence_compiler();
        __builtin_amdgcn_s_barrier();
    }
    __syncthreads();

    const int crow0 = bm + wr + (lane >> 4) * 4;
    const int ccol0 = bn + wc + (lane & 15);
    float ls[4] = {}, lq[4] = {};
#pragma unroll
    for (int i = 0; i < 4; ++i)
#pragma unroll
        for (int jn = 0; jn < 4; ++jn) {
            int col = ccol0 + jn * 16;
#pragma unroll
            for (int r = 0; r < 4; ++r) {
                float v = acc[i][jn][r];
                ls[jn] += v; lq[jn] += v * v;
                Y[(size_t)(crow0 + i * 16 + r) * ldY + col] = f2bf(v);
            }
        }
#pragma unroll
    for (int jn = 0; jn < 4; ++jn) {
        ls[jn] += __shfl_xor(ls[jn], 16, 64); ls[jn] += __shfl_xor(ls[jn], 32, 64);
        lq[jn] += __shfl_xor(lq[jn], 16, 64); lq[jn] += __shfl_xor(lq[jn], 32, 64);
    }
    float* red = (float*)&Asm[0][0];
    if (lane < 16) {
#pragma unroll
        for (int jn = 0; jn < 4; ++jn) {
            red[((w * 16 + lane) * 4 + jn) * 2 + 0] = ls[jn];
            red[((w * 16 + lane) * 4 + jn) * 2 + 1] = lq[jn];
        }
    }
    __syncthreads();
    if (tid < 256) {
        int colhalf = tid & 127, isq = tid >> 7;
        int pair = colhalf >> 6, within = colhalf & 63;
        int l16 = within & 15, jn = within >> 4;
        int w0 = pair ? 1 : 0, w1 = pair ? 3 : 2;
        float s = red[((w0 * 16 + l16) * 4 + jn) * 2 + isq]
                + red[((w1 * 16 + l16) * 4 + jn) * 2 + isq];
        atomicAdd(&accOut[(bn + colhalf) + isq * sqoff], s);
    }
}

// ---------------------------------------------------------------- conv1 ------
// R10-proven kernel: gload_lds halo staged 9 phases early, B dbuf 1 phase
// early, counted-vmcnt 2-barrier phases, fused column stats.
__global__ __launch_bounds__(256) void k_convmma(
    const ushort_t* __restrict__ X, const ushort_t* __restrict__ Wt,
    ushort_t* __restrict__ Yb, const float* __restrict__ bias,
    const ushort_t* __restrict__ zp, float* __restrict__ accp)
{
    __shared__ ushort_t Asm[2][192 * 64];
    __shared__ ushort_t Bsm[2][128 * 64];
    const int tid  = threadIdx.x;
    const int w    = tid >> 6;
    const int lane = tid & 63;
    const int virt = xcd_virt(blockIdx.x, 2200);
    const int pi   = virt >> 1;
    const int bn   = (virt & 1) * 128;
    const int b    = pi / 275;
    const int rem  = pi % 275;
    const int th   = rem / 11, tw = rem % 11;
    const int y0   = th * 8 - 1, x0 = tw * 16 - 1;
    const int hb   = (w >> 1) * 4;
    const int wc   = (w & 1) * 64;

    const int qlog = (lane & 7) ^ (lane >> 3);
    const ushort_t* asrc[6];
#pragma unroll
    for (int j = 0; j < 6; ++j) {
        int hr = j * 32 + w * 8 + (lane >> 3);
        int ph = hr / 18, pw = hr % 18;
        int y = y0 + ph, x = x0 + pw;
        bool ok = (hr < 180) && ((unsigned)y < (unsigned)H_DIM) &&
                  ((unsigned)x < (unsigned)W_DIM);
        asrc[j] = ok ? X + ((size_t)b * HW + (size_t)y * W_DIM + x) * 256 + qlog * 8
                     : zp + (lane & 7) * 8;
    }
    const ushort_t* bsrc = Wt + (size_t)(bn + w * 8 + (lane >> 3)) * 256 + qlog * 8;
    const int lo = (w * 8) * 64;

#pragma unroll
    for (int j = 0; j < 6; ++j)
        async16(asrc[j], &Asm[0][(j * 32) * 64 + lo]);
#pragma unroll
    for (int j = 0; j < 4; ++j)
        async16(bsrc + (size_t)j * 8192, &Bsm[0][(j * 32) * 64 + lo]);

    f32x4 acc[4][4] = {};
    for (int kc = 0; kc < 4; ++kc) {
        const ushort_t* acur = Asm[kc & 1];
#pragma unroll
        for (int pos = 0; pos < 9; ++pos) {
            const ushort_t* bcur = Bsm[(kc + pos) & 1];
            ushort_t* bnxt = (ushort_t*)Bsm[(kc + pos + 1) & 1];
            if (pos == 0) {
                if (kc < 3) {
#pragma unroll
                    for (int j = 0; j < 6; ++j)
                        async16(asrc[j] + (kc + 1) * 64,
                                &Asm[(kc + 1) & 1][(j * 32) * 64 + lo]);
#pragma unroll
                    for (int j = 0; j < 4; ++j)
                        async16(bsrc + (size_t)65536 + kc * 64 + j * 8192,
                                bnxt + (j * 32) * 64 + lo);
                    wait_vmcnt10();
                } else {
#pragma unroll
                    for (int j = 0; j < 4; ++j)
                        async16(bsrc + (size_t)65536 + kc * 64 + j * 8192,
                                bnxt + (j * 32) * 64 + lo);
                    wait_vmcnt4();
                }
            } else if (pos < 8) {
#pragma unroll
                for (int j = 0; j < 4; ++j)
                    async16(bsrc + (size_t)(pos + 1) * 65536 + kc * 64 + j * 8192,
                            bnxt + (j * 32) * 64 + lo);
                wait_vmcnt4();
            } else if (kc < 3) {
#pragma unroll
                for (int j = 0; j < 4; ++j)
                    async16(bsrc + (size_t)(kc + 1) * 64 + j * 8192,
                            bnxt + (j * 32) * 64 + lo);
                wait_vmcnt4();
            } else {
                wait_vmcnt0();
            }
            __builtin_amdgcn_s_barrier();
            const int dy = pos / 3 - 1, dx = pos % 3 - 1;
            __builtin_amdgcn_s_setprio(1);
#pragma unroll
            for (int ks = 0; ks < 2; ++ks) {
                const int q = ks * 4 + (lane >> 4);
                bf16x8 af[4], bfr[4];
#pragma unroll
                for (int i = 0; i < 4; ++i) {
                    int ri = (hb + i + 1 + dy) * 18 + 1 + dx + (lane & 15);
                    af[i] = *(const bf16x8*)&acur[ri * 64 + ((q ^ (ri & 7)) * 8)];
                }
#pragma unroll
                for (int jn = 0; jn < 4; ++jn) {
                    int rn = wc + jn * 16 + (lane & 15);
                    bfr[jn] = *(const bf16x8*)&bcur[rn * 64 + ((q ^ (rn & 7)) * 8)];
                }
#pragma unroll
                for (int i = 0; i < 4; ++i)
#pragma unroll
                    for (int jn = 0; jn < 4; ++jn)
                        acc[i][jn] = __builtin_amdgcn_mfma_f32_16x16x32_bf16(
                            af[i], bfr[jn], acc[i][jn], 0, 0, 0);
            }
            __builtin_amdgcn_s_setprio(0);
            memfence_compiler();
            __builtin_amdgcn_s_barrier();
        }
    }
    __syncthreads();

    const size_t sbase = (size_t)b * HW + (size_t)(th * 8) * W_DIM + tw * 16;
    const int colb = bn + wc + (lane & 15);
    const int wsub = (lane >> 4) * 4;
    float ls[4] = {}, lq[4] = {};
#pragma unroll
    for (int i = 0; i < 4; ++i) {
        int h = hb + i;
#pragma unroll
        for (int jn = 0; jn < 4; ++jn) {
            int col = colb + jn * 16;
            float bb = bias ? bias[col] : 0.f;
#pragma unroll
            for (int r = 0; r < 4; ++r) {
                size_t s = sbase + (size_t)h * W_DIM + wsub + r;
                float v = acc[i][jn][r] + bb;
                ls[jn] += v; lq[jn] += v * v;
                Yb[s * 256 + col] = f2bf(v);
            }
        }
    }
#pragma unroll
    for (int jn = 0; jn < 4; ++jn) {
        ls[jn] += __shfl_xor(ls[jn], 16, 64); ls[jn] += __shfl_xor(ls[jn], 32, 64);
        lq[jn] += __shfl_xor(lq[jn], 16, 64); lq[jn] += __shfl_xor(lq[jn], 32, 64);
    }
    float* red = (float*)&Asm[0][0];
    if (lane < 16) {
#pragma unroll
        for (int jn = 0; jn < 4; ++jn) {
            red[((w * 16 + lane) * 4 + jn) * 2 + 0] = ls[jn];
            red[((w * 16 + lane) * 4 + jn) * 2 + 1] = lq[jn];
        }
    }
    __syncthreads();
    if (tid < 256) {
        int colhalf = tid & 127, isq = tid >> 7;
        int pair = colhalf >> 6, within = colhalf & 63;
        int l16 = within & 15, jn = within >> 4;
        int w0 = pair ? 1 : 0, w1 = pair ? 3 : 2;
        float s = red[((w0 * 16 + l16) * 4 + jn) * 2 + isq]
                + red[((w1 * 16 + l16) * 4 + jn) * 2 + isq];
        atomicAdd(&accp[(bn + colhalf) + isq * 256], s);
    }
}

// conv2: proven R8 kernel — BN-fused reg-staged halo (8h x 16w patches)
__global__ __launch_bounds__(256) void k_convmma_bn(
    const ushort_t* __restrict__ X, const float* __restrict__ par,
    const ushort_t* __restrict__ Wt,
    ushort_t* __restrict__ Yb, const float* __restrict__ bias,
    const ushort_t* __restrict__ zp, float* __restrict__ accp)
{
    __shared__ ushort_t Asm[2][192 * 64];
    __shared__ ushort_t Bsm[2][128 * 64];
    const int tid  = threadIdx.x;
    const int w    = tid >> 6;
    const int lane = tid & 63;
    const int virt = xcd_virt(blockIdx.x, 2200);
    const int pi   = virt >> 1;
    const int bn   = (virt & 1) * 128;
    const int b    = pi / 275;
    const int rem  = pi % 275;
    const int th   = rem / 11, tw = rem % 11;
    const int y0   = th * 8 - 1, x0 = tw * 16 - 1;
    const int hb   = (w >> 1) * 4;
    const int wc   = (w & 1) * 64;

    const int qlog = (lane & 7) ^ (lane >> 3);
    const ushort_t* asrc[6];
    bool okj[6];
    int arow[6];
#pragma unroll
    for (int j = 0; j < 6; ++j) {
        int hr = j * 32 + w * 8 + (lane >> 3);
        arow[j] = hr;
        int ph = hr / 18, pw = hr % 18;
        int y = y0 + ph, x = x0 + pw;
        okj[j] = (hr < 180) && ((unsigned)y < (unsigned)H_DIM) &&
                 ((unsigned)x < (unsigned)W_DIM);
        asrc[j] = okj[j] ? X + ((size_t)b * HW + (size_t)y * W_DIM + x) * 256 + qlog * 8
                         : zp + (lane & 7) * 8;
    }
    const ushort_t* bsrc = Wt + (size_t)(bn + w * 8 + (lane >> 3)) * 256 + qlog * 8;
    const int lo = (w * 8) * 64;
    const int lsub = (lane & 7) * 8;
    const bf16x8 zv = 0;

    bf16x8 areg[6];
#pragma unroll
    for (int j = 0; j < 6; ++j) areg[j] = *(const bf16x8*)(asrc[j]);
#pragma unroll
    for (int j = 0; j < 4; ++j)
        async16(bsrc + (size_t)j * 8192, &Bsm[0][(j * 32) * 64 + lo]);
    {
        const int cb = qlog * 8;
#pragma unroll
        for (int j = 0; j < 6; ++j)
            *(bf16x8*)&Asm[0][arow[j] * 64 + lsub] =
                okj[j] ? bnrelu8(areg[j], par + cb, par + 256 + cb) : zv;
    }
    wait_lgkm0();

    f32x4 acc[4][4] = {};
#pragma unroll
    for (int kc = 0; kc < 4; ++kc) {
        const ushort_t* acur = Asm[kc & 1];
#pragma unroll
        for (int pos = 0; pos < 9; ++pos) {
            const ushort_t* bcur = Bsm[(kc + pos) & 1];
            ushort_t* bnxt = (ushort_t*)Bsm[(kc + pos + 1) & 1];
            if (pos < 8) {
#pragma unroll
                for (int j = 0; j < 4; ++j)
                    async16(bsrc + (size_t)(pos + 1) * 65536 + kc * 64 + j * 8192,
                            bnxt + (j * 32) * 64 + lo);
            } else if (kc < 3) {
#pragma unroll
                for (int j = 0; j < 4; ++j)
                    async16(bsrc + (size_t)(kc + 1) * 64 + j * 8192,
                            bnxt + (j * 32) * 64 + lo);
            }
            if (pos == 5 && kc < 3) {
#pragma unroll
                for (int j = 0; j < 6; ++j)
                    areg[j] = *(const bf16x8*)(asrc[j] + (kc + 1) * 64);
            }
            if (kc == 3 && pos == 8)      wait_vmcnt0();
            else if (pos == 6 && kc < 3)  wait_vmcnt10();
            else                          wait_vmcnt4();
            __builtin_amdgcn_s_barrier();
            const int dy = pos / 3 - 1, dx = pos % 3 - 1;
            __builtin_amdgcn_s_setprio(1);
#pragma unroll
            for (int ks = 0; ks < 2; ++ks) {
                const int q = ks * 4 + (lane >> 4);
                bf16x8 af[4], bfr[4];
#pragma unroll
                for (int i = 0; i < 4; ++i) {
                    int ri = (hb + i + 1 + dy) * 18 + 1 + dx + (lane & 15);
                    af[i] = *(const bf16x8*)&acur[ri * 64 + ((q ^ (ri & 7)) * 8)];
                }
#pragma unroll
                for (int jn = 0; jn < 4; ++jn) {
                    int rn = wc + jn * 16 + (lane & 15);
                    bfr[jn] = *(const bf16x8*)&bcur[rn * 64 + ((q ^ (rn & 7)) * 8)];
                }
#pragma unroll
                for (int i = 0; i < 4; ++i)
#pragma unroll
                    for (int jn = 0; jn < 4; ++jn)
                        acc[i][jn] = __builtin_amdgcn_mfma_f32_16x16x32_bf16(
                            af[i], bfr[jn], acc[i][jn], 0, 0, 0);
            }
            __builtin_amdgcn_s_setprio(0);
            if (pos == 8 && kc < 3) {
                const int cb = (kc + 1) * 64 + qlog * 8;
#pragma unroll
                for (int j = 0; j < 6; ++j)
                    *(bf16x8*)&Asm[(kc + 1) & 1][arow[j] * 64 + lsub] =
                        okj[j] ? bnrelu8(areg[j], par + cb, par + 256 + cb) : zv;
                wait_lgkm0();
            }
            memfence_compiler();
            __builtin_amdgcn_s_barrier();
        }
    }
    __syncthreads();

    const size_t sbase = (size_t)b * HW + (size_t)(th * 8) * W_DIM + tw * 16;
    const int colb = bn + wc + (lane & 15);
    const int wsub = (lane >> 4) * 4;
    float ls[4] = {}, lq[4] = {};
#pragma unroll
    for (int i = 0; i < 4; ++i) {
        int h = hb + i;
#pragma unroll
        for (int jn = 0; jn < 4; ++jn) {
            int col = colb + jn * 16;
            float bb = bias ? bias[col] : 0.f;
#pragma unroll
            for (int r = 0; r < 4; ++r) {
                size_t s = sbase + (size_t)h * W_DIM + wsub + r;
                float v = acc[i][jn][r] + bb;
                ls[jn] += v; lq[jn] += v * v;
                Yb[s * 256 + col] = f2bf(v);
            }
        }
    }
#pragma unroll
    for (int jn = 0; jn < 4; ++jn) {
        ls[jn] += __shfl_xor(ls[jn], 16, 64); ls[jn] += __shfl_xor(ls[jn], 32, 64);
        lq[jn] += __shfl_xor(lq[jn], 16, 64); lq[jn] += __shfl_xor(lq[jn], 32, 64);
    }
    float* red = (float*)&Asm[0][0];
    if (lane < 16) {
#pragma unroll
        for (int jn = 0; jn < 4; ++jn) {
            red[((w * 16 + lane) * 4 + jn) * 2 + 0] = ls[jn];
            red[((w * 16 + lane) * 4 + jn) * 2 + 1] = lq[jn];
        }
    }
    __syncthreads();
    if (tid < 256) {
        int colhalf = tid & 127, isq = tid >> 7;
        int pair = colhalf >> 6, within = colhalf & 63;
        int l16 = within & 15, jn = within >> 4;
        int w0 = pair ? 1 : 0, w1 = pair ? 3 : 2;
        float s = red[((w0 * 16 + l16) * 4 + jn) * 2 + isq]
                + red[((w1 * 16 + l16) * 4 + jn) * 2 + isq];
        atomicAdd(&accp[(bn + colhalf) + isq * 256], s);
    }
}

// ------------------------------------------------- merged weight cast (1 launch)
__global__ __launch_bounds__(256) void k_castw_all(
    const float* __restrict__ cw1, const float* __restrict__ cw2,
    const float* __restrict__ shw1, const float* __restrict__ gw1,
    const float* __restrict__ shw2, const float* __restrict__ gw2,
    ushort_t* __restrict__ WT1, ushort_t* __restrict__ WT2,
    ushort_t* __restrict__ WCAT, ushort_t* __restrict__ WS2,
    ushort_t* __restrict__ WG2)
{
    const int bid = blockIdx.x, ci = threadIdx.x;
    const float* src; ushort_t* dst; int CO, pc;
    if (bid < 2304)      { src = cw1;  dst = WT1;          CO = 256; pc = bid; }
    else if (bid < 4608) { src = cw2;  dst = WT2;          CO = 256; pc = bid - 2304; }
    else if (bid < 4864) { src = shw1; dst = WCAT;         CO = 256; pc = bid - 4608; }
    else if (bid < 5120) { src = gw1;  dst = WCAT + 65536; CO = 256; pc = bid - 4864; }
    else if (bid < 5376) { src = shw2; dst = WS2;          CO = 256; pc = bid - 5120; }
    else                 { src = gw2;  dst = WG2;          CO = 128; pc = bid - 5376; }
    int co = pc % CO, pos = pc / CO;
    dst[(size_t)pc * 256 + ci] = f2bf(src[((size_t)pos * 256 + ci) * CO + co]);
}

// ---------------------------------------------------------------- BN params --
__global__ void k_bnparams(const float* __restrict__ acc,
                           const float* __restrict__ g,
                           const float* __restrict__ b,
                           float* __restrict__ par, int ncols)
{
    int c = threadIdx.x;
    if (c >= ncols) return;
    float m = acc[c] * INV_S;
    float v = acc[ncols + c] * INV_S - m * m;
    float sc = g[c] * rsqrtf(v + EPS);
    par[c] = sc;
    par[ncols + c] = b[c] - m * sc;
}

// ---------------------------------------------------------------- head -------
// R10-proven: in-kernel params for both branches, writes sp (bf16) to Xb
__global__ __launch_bounds__(256) void k_headfin(
    const ushort_t* __restrict__ B2, const ushort_t* __restrict__ B3,
    const float* __restrict__ acc1, const float* __restrict__ shg2,
    const float* __restrict__ shb2,
    const float* __restrict__ acc3, const float* __restrict__ gg2,
    const float* __restrict__ gb2,
    const float* __restrict__ shw3, const float* __restrict__ shb3,
    const float* __restrict__ gw3, const float* __restrict__ gb3,
    const ushort_t* __restrict__ Pb, ushort_t* __restrict__ Xb)
{
    __shared__ float parA[512], parB[256];
    const int t = threadIdx.x;
    {
        float m = acc1[t] * INV_S;
        float v = acc1[256 + t] * INV_S - m * m;
        float sc = shg2[t] * rsqrtf(v + EPS);
        parA[t] = sc; parA[256 + t] = shb2[t] - m * sc;
    }
    if (t < 128) {
        float m = acc3[t] * INV_S;
        float v = acc3[128 + t] * INV_S - m * m;
        float sc = gg2[t] * rsqrtf(v + EPS);
        parB[t] = sc; parB[128 + t] = gb2[t] - m * sc;
    }
    __syncthreads();

    const int wave = t >> 6;
    const int lane = t & 63;
    const int s = blockIdx.x * 4 + wave;
    const ushort_t* b2 = B2 + (size_t)s * 256;
    const ushort_t* b3 = B3 + (size_t)s * 128;
    float d1 = 0.f, d2 = 0.f;
    {
        ushort4 u = ((const ushort4*)b2)[lane];
        int c = lane * 4;
        float v0 = fmaxf(0.f, bf2f(u.x) * parA[c + 0] + parA[256 + c + 0]);
        float v1 = fmaxf(0.f, bf2f(u.y) * parA[c + 1] + parA[256 + c + 1]);
        float v2 = fmaxf(0.f, bf2f(u.z) * parA[c + 2] + parA[256 + c + 2]);
        float v3 = fmaxf(0.f, bf2f(u.w) * parA[c + 3] + parA[256 + c + 3]);
        d1 = v0 * shw3[(c + 0) * 9] + v1 * shw3[(c + 1) * 9]
           + v2 * shw3[(c + 2) * 9] + v3 * shw3[(c + 3) * 9];
    }
    {
        ushort2 u = ((const ushort2*)b3)[lane];
        int c = lane * 2;
        float v0 = fmaxf(0.f, bf2f(u.x) * parB[c + 0] + parB[128 + c + 0]);
        float v1 = fmaxf(0.f, bf2f(u.y) * parB[c + 1] + parB[128 + c + 1]);
        d2 = v0 * gw3[c + 0] + v1 * gw3[c + 1];
    }
#pragma unroll
    for (int off = 32; off > 0; off >>= 1) {
        d1 += __shfl_down(d1, off, 64);
        d2 += __shfl_down(d2, off, 64);
    }
    d1 = __shfl(d1, 0, 64);
    d2 = __shfl(d2, 0, 64);
    float shdc = d1 + shb3[0];
    float gaus = 1.f / (1.f + expf(-(d2 + gb3[0])));
    float factor = shdc * gaus;
    ushort4 pv = ((const ushort4*)(Pb + (size_t)s * 256))[lane];
    ushort4 o;
    o.x = f2bf(bf2f(pv.x) * factor);
    o.y = f2bf(bf2f(pv.y) * factor);
    o.z = f2bf(bf2f(pv.z) * factor);
    o.w = f2bf(bf2f(pv.w) * factor);
    ((ushort4*)(Xb + (size_t)s * 256))[lane] = o;
}

// ---------------------------------------------------------------- final ------
__global__ __launch_bounds__(256) void k_bnrelu_f32out(
    const ushort_t* __restrict__ Y, const float* __restrict__ acc5,
    const float* __restrict__ g, const float* __restrict__ b,
    float* __restrict__ out)
{
    __shared__ float par[512];
    const int t = threadIdx.x;
    {
        float m = acc5[t] * INV_S;
        float v = acc5[256 + t] * INV_S - m * m;
        float sc = g[t] * rsqrtf(v + EPS);
        par[t] = sc; par[256 + t] = b[t] - m * sc;
    }
    __syncthreads();
    size_t q = (size_t)blockIdx.x * 256 + t;
    int c = (int)(q & 63) * 4;
    ushort4 u = ((const ushort4*)Y)[q];
    float4 v;
    v.x = fmaxf(0.f, bf2f(u.x) * par[c + 0] + par[256 + c + 0]);
    v.y = fmaxf(0.f, bf2f(u.y) * par[c + 1] + par[256 + c + 1]);
    v.z = fmaxf(0.f, bf2f(u.z) * par[c + 2] + par[256 + c + 2]);
    v.w = fmaxf(0.f, bf2f(u.w) * par[c + 3] + par[256 + c + 3]);
    ((float4*)out)[q] = v;
}

// ---------------------------------------------------------------- launch -----
extern "C" void kernel_launch(void* const* d_in, const int* in_sizes, int n_in,
                              void* d_out, int out_size, void* d_ws, size_t ws_size,
                              hipStream_t stream)
{
    (void)in_sizes; (void)n_in; (void)out_size; (void)ws_size;
    const float* feats   = (const float*)d_in[0];
    const int*   cb      = (const int*)d_in[1];
    const int*   cy      = (const int*)d_in[2];
    const int*   cx      = (const int*)d_in[3];
    const float* sh_w1   = (const float*)d_in[4];
    const float* sh_g1   = (const float*)d_in[5];
    const float* sh_b1   = (const float*)d_in[6];
    const float* sh_w2   = (const float*)d_in[7];
    const float* sh_g2   = (const float*)d_in[8];
    const float* sh_b2   = (const float*)d_in[9];
    const float* sh_w3   = (const float*)d_in[10];
    const float* sh_bias3= (const float*)d_in[11];
    const float* g_w1    = (const float*)d_in[12];
    const float* g_g1    = (const float*)d_in[13];
    const float* g_b1    = (const float*)d_in[14];
    const float* g_w2    = (const float*)d_in[15];
    const float* g_g2    = (const float*)d_in[16];
    const float* g_b2    = (const float*)d_in[17];
    const float* g_w3    = (const float*)d_in[18];
    const float* g_bias3 = (const float*)d_in[19];
    const float* cw1     = (const float*)d_in[20];
    const float* c1_g    = (const float*)d_in[21];
    const float* c1_b    = (const float*)d_in[22];
    const float* cw2     = (const float*)d_in[23];
    const float* c2_bias = (const float*)d_in[24];
    const float* c2_g    = (const float*)d_in[25];
    const float* c2_b    = (const float*)d_in[26];

    float* out = (float*)d_out;
    float* ws  = (float*)d_ws;
    ushort_t* Pb   = (ushort_t*)(ws);                    // pooled bf16 [S][256]
    ushort_t* Bsh  = (ushort_t*)(ws + 18022400);         // SH1 raw / sp / conv2 out
    ushort_t* Bg   = (ushort_t*)(ws + 36044800);         // G1 raw
    ushort_t* Cb   = (ushort_t*)(ws + 54067200);         // SH2 raw
    ushort_t* FT   = (ushort_t*)(ws + 54067200);         // alias (pool phase)
    ushort_t* Db   = (ushort_t*)(ws + 72089600);         // G2 raw [S][128]
    int*      CNTi = (int*)(ws + 72089600);              // alias (pool phase)
    int*      PSL  = CNTi + S_TOT;
    int*      VID  = PSL + S_TOT * 8;
    ushort_t* Eb   = Pb;                                  // conv1 out (Pb dead)
    ushort_t* WCAT = (ushort_t*)(ws + 81100800);         // [512][256] layer-1
    ushort_t* WS2  = WCAT + 131072;
    ushort_t* WG2  = WS2 + 65536;                        // [128][256]
    ushort_t* WT1  = WG2 + 32768;                        // 9*256*256
    ushort_t* WT2  = WT1 + 589824;
    ushort_t* ZP   = WT2 + 589824;                       // 4KB zero page
    float*    ACC  = (float*)(ZP + 2048);                // 6 * 512
    float*    PAR  = ACC + 6 * 512;                      // conv1 BN params

    hipMemsetAsync(CNTi, 0, (size_t)S_TOT * 4, stream);
    hipMemsetAsync(ACC, 0, 6 * 512 * 4, stream);
    hipMemsetAsync(ZP, 0, 4096, stream);

    // weights -> bf16 [co][ci] (single merged launch)
    k_castw_all<<<5504, 256, 0, stream>>>(cw1, cw2, sh_w1, g_w1, sh_w2, g_w2,
                                          WT1, WT2, WCAT, WS2, WG2);

    // 1) pooling
    k_transpose<<<dim3(256, 4, 4), 256, 0, stream>>>(feats, FT);
    k_buildidx<<<NPTS / 256, 256, 0, stream>>>(cb, cy, cx, CNTi, PSL, VID);
    k_poolgather<<<S_TOT / 4, 256, 0, stream>>>(FT, CNTi, PSL, VID, Pb);

    // 2) merged layer-1 (SH1 | G1) raw outputs + stats
    k_gemmma<<<4400, 256, 0, stream>>>(Pb, WCAT, Bsh, Bg, 256, 4, 4400,
                                       ACC + 0 * 512, ACC + 2 * 512, 256);
    // 3+4) grouped SH-L2 (N=256) + G-L2 (N=128): bnrelu-on-the-fly + stats
    k_gemmma_bn2<<<3300, 256, 0, stream>>>(
        Bsh, ACC + 0 * 512, sh_g1, sh_b1, WS2, Cb, ACC + 1 * 512,
        Bg,  ACC + 2 * 512, g_g1,  g_b1,  WG2, Db, ACC + 3 * 512);
    // 5) head finalize (in-kernel params): sp (bf16) -> Bsh
    k_headfin<<<S_TOT / 4, 256, 0, stream>>>(Cb, Db,
                                             ACC + 1 * 512, sh_g2, sh_b2,
                                             ACC + 3 * 512, g_g2, g_b2,
                                             sh_w3, sh_bias3, g_w3, g_bias3,
                                             Pb, Bsh);
    // 6) conv1 (proven R10 gload_lds): Eb(=Pb) = conv3x3(Bsh) + stats ; params
    k_convmma<<<2200, 256, 0, stream>>>(Bsh, WT1, Eb, nullptr, ZP, ACC + 4 * 512);
    k_bnparams<<<1, 256, 0, stream>>>(ACC + 4 * 512, c1_g, c1_b, PAR, 256);
    // 7) conv2 (proven R8 BN-fused): Bsh = conv3x3(bnrelu(Eb)) + bias + stats
    k_convmma_bn<<<2200, 256, 0, stream>>>(Eb, PAR, WT2, Bsh, c2_bias, ZP,
                                           ACC + 5 * 512);
    // 8) final BN+ReLU -> f32 out (in-kernel params)
    k_bnrelu_f32out<<<35200, 256, 0, stream>>>(Bsh, ACC + 5 * 512, c2_g, c2_b, out);
}